// Round 5
// baseline (332.444 us; speedup 1.0000x reference)
//
#include <hip/hip_runtime.h>
#include <hip/hip_bf16.h>
#include <math.h>

#define H_ 64
#define W_ 64
#define CIN 128
#define COUT 256
#define NB 8
#define KK9 9
#define NPIX 4096        // H_*W_
#define KTOT 1152        // CIN*KK9
#define NCK 36           // K chunks of 32 (kk-major: k' = kk*128 + c)
#define KPAD 40          // padded K-row (shorts): 80B rows -> even bank-quad spread

typedef short short8_t __attribute__((ext_vector_type(8)));
typedef float floatx4 __attribute__((ext_vector_type(4)));

__device__ __forceinline__ unsigned short f2bf(float f) {
    union { float f; unsigned u; } v; v.f = f;
    unsigned r = v.u + 0x7FFF + ((v.u >> 16) & 1);   // RNE
    return (unsigned short)(r >> 16);
}
__device__ __forceinline__ float bf2f(unsigned short h) {
    union { unsigned u; float f; } v; v.u = ((unsigned)h) << 16;
    return v.f;
}

#if defined(__has_builtin)
#if __has_builtin(__builtin_amdgcn_global_load_lds)
#define HAVE_GLOAD_LDS 1
#endif
#endif

#ifdef HAVE_GLOAD_LDS
// direct global->LDS 16B/lane copy: LDS dest = wave-uniform base + lane*16 (m104)
__device__ __forceinline__ void gload_lds16(const unsigned int* g, unsigned int* l) {
    __builtin_amdgcn_global_load_lds(
        (const __attribute__((address_space(1))) unsigned int*)g,
        (__attribute__((address_space(3))) unsigned int*)l, 16, 0, 0);
}
#endif

// ---------------------------------------------------------------------------
// Kernel A: offset conv (18 ch) + modulation conv (9 ch), fused (fp32 direct).
// Writes py = dy + base_y, px = dx + base_x, mod = sigmoid(conv) to ws.
// ---------------------------------------------------------------------------
__global__ __launch_bounds__(256) void k_offmod(
    const float* __restrict__ x, const float* __restrict__ w_off,
    const float* __restrict__ b_off, const float* __restrict__ w_mod,
    const float* __restrict__ b_mod, float* __restrict__ ppy,
    float* __restrict__ ppx, float* __restrict__ pmod)
{
    __shared__ float xp[16][10][12];   // 16 c-chunk, 10x10 patch, pad->12
    __shared__ float wb[27][16][12];   // 27 ch, 16 c, 9 taps pad->12
    const int t = threadIdx.x;
    const int tx = blockIdx.x, ty = blockIdx.y, b = blockIdx.z;
    const int q = t & 15, g = t >> 4;          // 16 px-quads x 16 ch-groups
    const int lpy = q >> 1, lpx4 = (q & 1) * 4;
    float acc[2][4] = {};

    for (int cc = 0; cc < CIN; cc += 16) {
        __syncthreads();
        for (int idx = t; idx < 1600; idx += 256) {
            int c = idx / 100, r = (idx % 100) / 10, col = idx % 10;
            int gy = ty * 8 - 1 + r, gx = tx * 8 - 1 + col;
            float v = 0.f;
            if (gy >= 0 && gy < H_ && gx >= 0 && gx < W_)
                v = x[((b * CIN + cc + c) * H_ + gy) * W_ + gx];
            xp[c][r][col] = v;
        }
        for (int idx = t; idx < 27 * 16 * 9; idx += 256) {
            int ch = idx / 144, rr = idx % 144, c = rr / 9, tap = rr % 9;
            wb[ch][c][tap] = (ch < 18)
                ? w_off[(ch * CIN + cc + c) * 9 + tap]
                : w_mod[((ch - 18) * CIN + cc + c) * 9 + tap];
        }
        __syncthreads();

        for (int c = 0; c < 16; ++c) {
            float xv[3][8];
            #pragma unroll
            for (int ky = 0; ky < 3; ++ky) {
                float4 v0 = *(const float4*)&xp[c][lpy + ky][lpx4];
                float4 v1 = *(const float4*)&xp[c][lpy + ky][lpx4 + 4];
                xv[ky][0] = v0.x; xv[ky][1] = v0.y; xv[ky][2] = v0.z; xv[ky][3] = v0.w;
                xv[ky][4] = v1.x; xv[ky][5] = v1.y; xv[ky][6] = v1.z; xv[ky][7] = v1.w;
            }
            #pragma unroll
            for (int i = 0; i < 2; ++i) {
                int ch = g + 16 * i;
                if (ch < 27) {
                    const float* wr = &wb[ch][c][0];
                    #pragma unroll
                    for (int ky = 0; ky < 3; ++ky)
                        #pragma unroll
                        for (int kx = 0; kx < 3; ++kx) {
                            float wv = wr[ky * 3 + kx];
                            #pragma unroll
                            for (int p = 0; p < 4; ++p)
                                acc[i][p] += xv[ky][p + kx] * wv;
                        }
                }
            }
        }
    }

    const int ho = ty * 8 + lpy;
    #pragma unroll
    for (int i = 0; i < 2; ++i) {
        int ch = g + 16 * i;
        if (ch >= 27) continue;
        #pragma unroll
        for (int p = 0; p < 4; ++p) {
            int wo = tx * 8 + lpx4 + p;
            int pix = ho * W_ + wo;
            if (ch < 18) {
                float v = acc[i][p] + b_off[ch];
                int kk = ch >> 1;
                if ((ch & 1) == 0)
                    ppy[(b * KK9 + kk) * NPIX + pix] = v + (float)(ho - 1 + kk / 3);
                else
                    ppx[(b * KK9 + kk) * NPIX + pix] = v + (float)(wo - 1 + kk % 3);
            } else {
                int km = ch - 18;
                float v = acc[i][p] + b_mod[km];
                pmod[(b * KK9 + km) * NPIX + pix] = 1.f / (1.f + expf(-v));
            }
        }
    }
}

// ---------------------------------------------------------------------------
// Prep: w_dc [256][1152] -> bf16 hi/lo split, kk-major chunked+padded:
// wsplit flat idx = ((ck*2+hl)*COUT+o)*KPAD + kl ; k' = ck*32+kl = kk*128+c.
// One thread per OUTPUT short (coalesced writes); pads written as 0.
// ---------------------------------------------------------------------------
__global__ __launch_bounds__(256) void k_prep(
    const float* __restrict__ w_dc, unsigned short* __restrict__ wsplit)
{
    int idx = blockIdx.x * 256 + threadIdx.x;        // 737280 total
    int kl = idx % KPAD;
    int rest = idx / KPAD;                           // (ck*2+hl)*256 + o
    int o = rest & 255;
    int rest2 = rest >> 8;
    int hl = rest2 & 1, ck = rest2 >> 1;
    unsigned short v = 0;
    if (kl < 32) {
        int kp = ck * 32 + kl;                       // k' in [0,1152)
        int kk = kp >> 7, c = kp & 127;              // k' = kk*128 + c
        float w = w_dc[o * KTOT + c * 9 + kk];       // original k = c*9 + kk
        unsigned short hi = f2bf(w);
        v = hl ? f2bf(w - bf2f(hi)) : hi;
    }
    wsplit[idx] = v;
}

// ---------------------------------------------------------------------------
// Kernel B: fused bilinear-sample + modulate + split-bf16 MFMA GEMM
// C[o][px] = sum_k W[o][k] * S[k][px],  o in [0,256), px tile of 64, K=1152.
// kk-major K ordering: chunk ck has kk = ck>>2 constant -> bilinear setup
// hoisted per-kk (computed once per 4 chunks).
// Block: 256 thr = 4 waves; wave wm computes o in [wm*64,(wm+1)*64) x 64 px.
// bf16x3: acc += Whi*Shi + Whi*Slo + Wlo*Shi  (fp32 MFMA accumulate).
// ---------------------------------------------------------------------------
__global__ __launch_bounds__(256, 2) void k_main(
    const float* __restrict__ x, const unsigned short* __restrict__ wsplit,
    const float* __restrict__ ppy, const float* __restrict__ ppx,
    const float* __restrict__ pmod, float* __restrict__ out,
    float* __restrict__ gsum, float* __restrict__ gsq)
{
    __shared__ __align__(16) unsigned short Wsp[2 * COUT * KPAD]; // hi | lo, 40960 B
    __shared__ __align__(16) unsigned short Ssp[2 * 64 * KPAD];   // hi | lo, 10240 B
    __shared__ float ppl[3][KK9][64];
    __shared__ float redS[COUT], redQ[COUT];

    const int t = threadIdx.x;
    // XCD-affine: blocks with same (blockIdx&7) share batch b -> x[b] (2 MB)
    // tends to stay resident in one XCD's 4 MiB L2.
    const int b = blockIdx.x & 7;
    const int pix0 = (blockIdx.x >> 3) * 64;
    const int lane = t & 63, wm = t >> 6;

    // stage py/px/mod for this px tile
    for (int idx = t; idx < 3 * KK9 * 64; idx += 256) {
        int arr = idx / (KK9 * 64), rem = idx - arr * (KK9 * 64);
        int kk = rem >> 6, p = rem & 63;
        const float* src = (arr == 0) ? ppy : (arr == 1) ? ppx : pmod;
        ppl[arr][kk][p] = src[(b * KK9 + kk) * NPIX + pix0 + p];
    }
    __syncthreads();   // ppl ready before any setup reads it

    floatx4 acc[4][4] = {};   // [mi][ni]
    const float* xb = x + b * CIN * NPIX;
    const int pxl = t & 63, kg = t >> 6;      // sampling ownership
    const int o_lane = lane & 15, g4 = lane >> 4;

    for (int kk = 0; kk < KK9; ++kk) {
        // ---- per-kk bilinear setup for own pixel (valid folded into weights,
        // indices clamped = reference's clip-then-mask semantics; mod folded)
        float py = ppl[0][kk][pxl];
        float px = ppl[1][kk][pxl];
        float m  = ppl[2][kk][pxl];
        float y0f = floorf(py), x0f = floorf(px);
        float wy1 = py - y0f, wx1 = px - x0f;
        float wy0 = 1.f - wy1, wx0 = 1.f - wx1;
        int y0 = (int)y0f, x0 = (int)x0f;
        bool y0v = (unsigned)y0 < (unsigned)H_;
        bool y1v = (unsigned)(y0 + 1) < (unsigned)H_;
        bool x0v = (unsigned)x0 < (unsigned)W_;
        bool x1v = (unsigned)(x0 + 1) < (unsigned)W_;
        float w00 = (y0v && x0v) ? wy0 * wx0 * m : 0.f;
        float w01 = (y0v && x1v) ? wy0 * wx1 * m : 0.f;
        float w10 = (y1v && x0v) ? wy1 * wx0 * m : 0.f;
        float w11 = (y1v && x1v) ? wy1 * wx1 * m : 0.f;
        int y0c = min(max(y0, 0), H_ - 1), y1c = min(max(y0 + 1, 0), H_ - 1);
        int x0c = min(max(x0, 0), W_ - 1), x1c = min(max(x0 + 1, 0), W_ - 1);
        int a00 = y0c * W_ + x0c, a01 = y0c * W_ + x1c;
        int a10 = y1c * W_ + x0c, a11 = y1c * W_ + x1c;

        for (int sub = 0; sub < 4; ++sub) {
            const int ck = kk * 4 + sub;
            __syncthreads();   // all waves done reading Wsp/Ssp of prev chunk
            // ---- stage W chunk (hi+lo, 40 x 1KiB slices) into LDS
            {
                const unsigned short* wsrc = wsplit + ck * (2 * COUT * KPAD);
#ifdef HAVE_GLOAD_LDS
                #pragma unroll
                for (int i = 0; i < 10; ++i) {
                    int slice = i * 4 + wm;
                    gload_lds16((const unsigned int*)(wsrc + slice * 512 + lane * 8),
                                (unsigned int*)(Wsp + slice * 512));
                }
#else
                const float4* s4 = (const float4*)wsrc;
                float4* d4 = (float4*)Wsp;
                #pragma unroll
                for (int i = 0; i < 10; ++i)
                    d4[i * 256 + t] = s4[i * 256 + t];
#endif
            }
            // ---- sample 8 consecutive channels (c0 wave-uniform plane base)
            {
                const int c0 = sub * 32 + kg * 8;
                const float* pl = xb + c0 * NPIX;
                unsigned short hs[8], ls[8];
                #pragma unroll
                for (int j = 0; j < 8; ++j) {
                    float s = pl[a00] * w00 + pl[a01] * w01 +
                              pl[a10] * w10 + pl[a11] * w11;
                    // truncation hi/lo split (err ~2^-15, same order as
                    // dropped lo*lo term)
                    union { float f; unsigned u; } su; su.f = s;
                    hs[j] = (unsigned short)(su.u >> 16);
                    union { unsigned u; float f; } hf; hf.u = su.u & 0xFFFF0000u;
                    union { float f; unsigned u; } du; du.f = s - hf.f;
                    ls[j] = (unsigned short)(du.u >> 16);
                    pl += NPIX;
                }
                union { unsigned short u[8]; short8_t v; } ph, plo;
                #pragma unroll
                for (int j = 0; j < 8; ++j) { ph.u[j] = hs[j]; plo.u[j] = ls[j]; }
                *(short8_t*)(Ssp + pxl * KPAD + kg * 8) = ph.v;
                *(short8_t*)(Ssp + 64 * KPAD + pxl * KPAD + kg * 8) = plo.v;
            }
            __syncthreads();   // drains vmcnt (gload_lds) + lgkmcnt (ds_write)

            // ---- MFMA: wave wm covers o in [wm*64, wm*64+64), px tile 64
            // A-frag (W): row = o_lane, k = g4*8+j ; B-frag (S): col = o_lane,
            // k = g4*8+j ; C/D: col = lane&15 (px), row = g4*4+reg (o). [m89]
            short8_t bh[4], bl[4];
            #pragma unroll
            for (int ni = 0; ni < 4; ++ni) {
                int pxf = ni * 16 + o_lane;
                bh[ni] = *(const short8_t*)(Ssp + pxf * KPAD + g4 * 8);
                bl[ni] = *(const short8_t*)(Ssp + 64 * KPAD + pxf * KPAD + g4 * 8);
            }
            #pragma unroll
            for (int mi = 0; mi < 4; ++mi) {
                int of = wm * 64 + mi * 16 + o_lane;
                short8_t ah = *(const short8_t*)(Wsp + of * KPAD + g4 * 8);
                short8_t al = *(const short8_t*)(Wsp + COUT * KPAD + of * KPAD + g4 * 8);
                #pragma unroll
                for (int ni = 0; ni < 4; ++ni) {
                    acc[mi][ni] = __builtin_amdgcn_mfma_f32_16x16x32_bf16(
                        ah, bh[ni], acc[mi][ni], 0, 0, 0);
                    acc[mi][ni] = __builtin_amdgcn_mfma_f32_16x16x32_bf16(
                        ah, bl[ni], acc[mi][ni], 0, 0, 0);
                    acc[mi][ni] = __builtin_amdgcn_mfma_f32_16x16x32_bf16(
                        al, bh[ni], acc[mi][ni], 0, 0, 0);
                }
            }
        }
    }

    // ---- BN partial sums: sum over px within lane, butterfly over lane bits
    // 0-3 (the px dimension). Each output channel o is then held by exactly one
    // lane of one wave (o = wm*64+mi*16+g4*4+r is a bijection) -> plain stores.
    #pragma unroll
    for (int mi = 0; mi < 4; ++mi) {
        #pragma unroll
        for (int r = 0; r < 4; ++r) {
            float s = 0.f, q = 0.f;
            #pragma unroll
            for (int ni = 0; ni < 4; ++ni) {
                float v = acc[mi][ni][r];
                s += v; q += v * v;
            }
            s += __shfl_xor(s, 1); q += __shfl_xor(q, 1);
            s += __shfl_xor(s, 2); q += __shfl_xor(q, 2);
            s += __shfl_xor(s, 4); q += __shfl_xor(q, 4);
            s += __shfl_xor(s, 8); q += __shfl_xor(q, 8);
            if (o_lane == 0) {
                int o = wm * 64 + mi * 16 + g4 * 4 + r;
                redS[o] = s;
                redQ[o] = q;
            }
        }
    }
    __syncthreads();
    if (t < COUT) {
        atomicAdd(&gsum[t], redS[t]);
        atomicAdd(&gsq[t],  redQ[t]);
    }

    // ---- store raw GEMM output (BN applied later by k_bnact)
    #pragma unroll
    for (int mi = 0; mi < 4; ++mi) {
        int o_base = wm * 64 + mi * 16 + g4 * 4;
        #pragma unroll
        for (int ni = 0; ni < 4; ++ni) {
            int px = pix0 + ni * 16 + o_lane;
            #pragma unroll
            for (int r = 0; r < 4; ++r)
                out[(b * COUT + o_base + r) * NPIX + px] = acc[mi][ni][r];
        }
    }
}

// ---------------------------------------------------------------------------
// Kernel C: in-place BN (from accumulated sums) + affine + SiLU, float4.
// ---------------------------------------------------------------------------
__global__ __launch_bounds__(256) void k_bnact(
    float* __restrict__ out, const float* __restrict__ gsum,
    const float* __restrict__ gsq, const float* __restrict__ gamma,
    const float* __restrict__ beta)
{
    int idx = blockIdx.x * 256 + threadIdx.x;     // float4 index, 2097152 total
    int o = (idx >> 10) & 255;
    const float invn = 1.f / 32768.f;
    float mean = gsum[o] * invn;
    float var = gsq[o] * invn - mean * mean;
    float scale = gamma[o] * rsqrtf(var + 1e-5f);
    float shift = beta[o] - mean * scale;
    float4* p = (float4*)out;
    float4 v = p[idx];
    float y;
    y = v.x * scale + shift; v.x = y / (1.f + expf(-y));
    y = v.y * scale + shift; v.y = y / (1.f + expf(-y));
    y = v.z * scale + shift; v.z = y / (1.f + expf(-y));
    y = v.w * scale + shift; v.w = y / (1.f + expf(-y));
    p[idx] = v;
}

extern "C" void kernel_launch(void* const* d_in, const int* in_sizes, int n_in,
                              void* d_out, int out_size, void* d_ws, size_t ws_size,
                              hipStream_t stream)
{
    (void)in_sizes; (void)n_in; (void)out_size; (void)ws_size;
    const float* x     = (const float*)d_in[0];
    const float* w_off = (const float*)d_in[1];
    const float* b_off = (const float*)d_in[2];
    const float* w_mod = (const float*)d_in[3];
    const float* b_mod = (const float*)d_in[4];
    const float* w_dc  = (const float*)d_in[5];
    const float* gamma = (const float*)d_in[6];
    const float* beta  = (const float*)d_in[7];
    float* out = (float*)d_out;
    float* ws  = (float*)d_ws;

    const int NPK = NB * KK9 * NPIX;              // 294912
    float* ppy  = ws;
    float* ppx  = ws + NPK;
    float* pmod = ws + 2 * NPK;
    unsigned short* wsplit = (unsigned short*)(ws + 3 * NPK);  // 737280 shorts
    float* gsum = ws + 3 * NPK + 368640;
    float* gsq  = gsum + 256;

    hipMemsetAsync(gsum, 0, 512 * sizeof(float), stream);
    hipLaunchKernelGGL(k_offmod, dim3(8, 8, NB), dim3(256), 0, stream,
                       x, w_off, b_off, w_mod, b_mod, ppy, ppx, pmod);
    hipLaunchKernelGGL(k_prep, dim3(2880), dim3(256), 0, stream,
                       w_dc, wsplit);
    hipLaunchKernelGGL(k_main, dim3(512), dim3(256), 0, stream,
                       x, wsplit, ppy, ppx, pmod, out, gsum, gsq);
    hipLaunchKernelGGL(k_bnact, dim3(8192), dim3(256), 0, stream,
                       out, gsum, gsq, gamma, beta);
}